// Round 1
// baseline (3535.820 us; speedup 1.0000x reference)
//
#include <hip/hip_runtime.h>
#include <hip/hip_bf16.h>
#include <math.h>

#define Bn 2
#define Hn 56
#define Wn 56
#define Cn 256
#define Nh 8
#define Dh 32
#define Fn 1024
#define Ln (Hn*Wn)          // 3136
#define Mrows (Bn*Ln)       // 6272
#define SCALING_K 0.17677669529663687f   // 32^-0.5

// ---------------- depthwise conv (3x3 or 5x5), optional residual add ----------------
__global__ void dwconv_kernel(const float* __restrict__ in, const float* __restrict__ wgt,
                              const float* __restrict__ bias, float* __restrict__ out,
                              int C, int KS, int pad, int addin)
{
    int idx = blockIdx.x * blockDim.x + threadIdx.x;
    int c4 = C >> 2;
    int c = (idx % c4) << 2;
    int rest = idx / c4;
    int w = rest % Wn; rest /= Wn;
    int h = rest % Hn;
    int b = rest / Hn;
    if (b >= Bn) return;
    float4 acc = *(const float4*)&bias[c];
    for (int dh = 0; dh < KS; ++dh) {
        int hh = h + dh - pad;
        if (hh < 0 || hh >= Hn) continue;
        for (int dw = 0; dw < KS; ++dw) {
            int ww = w + dw - pad;
            if (ww < 0 || ww >= Wn) continue;
            float4 xv = *(const float4*)&in[(((size_t)b*Hn + hh)*Wn + ww)*C + c];
            float4 wv = *(const float4*)&wgt[(size_t)(dh*KS + dw)*C + c];
            acc.x += xv.x*wv.x; acc.y += xv.y*wv.y; acc.z += xv.z*wv.z; acc.w += xv.w*wv.w;
        }
    }
    size_t o = (((size_t)b*Hn + h)*Wn + w)*C + c;
    if (addin) {
        float4 xv = *(const float4*)&in[o];
        acc.x += xv.x; acc.y += xv.y; acc.z += xv.z; acc.w += xv.w;
    }
    *(float4*)&out[o] = acc;
}

// ---------------- layernorm over C=256, one block per row ----------------
__global__ __launch_bounds__(256) void ln_kernel(const float* __restrict__ in,
    const float* __restrict__ g, const float* __restrict__ b, float* __restrict__ out)
{
    int row = blockIdx.x;
    int t = threadIdx.x;
    float v = in[(size_t)row*Cn + t];
    float s1 = v, s2 = v*v;
    for (int m = 1; m < 64; m <<= 1) {
        s1 += __shfl_xor(s1, m);
        s2 += __shfl_xor(s2, m);
    }
    __shared__ float w1s[4], w2s[4];
    if ((t & 63) == 0) { w1s[t>>6] = s1; w2s[t>>6] = s2; }
    __syncthreads();
    s1 = w1s[0]+w1s[1]+w1s[2]+w1s[3];
    s2 = w2s[0]+w2s[1]+w2s[2]+w2s[3];
    float mean = s1 * (1.0f/Cn);
    float var  = s2 * (1.0f/Cn) - mean*mean;
    float r = rsqrtf(var + 1e-6f);
    out[(size_t)row*Cn + t] = (v - mean) * r * g[t] + b[t];
}

// ---------------- fp32 tiled GEMM: out = epi(((A[+A2]) @ W + bias)*scale) [+resid] ----------------
// tile 64x64, BK=16, 256 threads, 4x4 micro-tile
__global__ __launch_bounds__(256) void gemm_kernel(
    const float* __restrict__ A, const float* __restrict__ A2,
    const float* __restrict__ W, const float* __restrict__ bias,
    const float* __restrict__ resid, float* __restrict__ out,
    int M, int K, int N, float scale, int gelu_flag)
{
    __shared__ float As[16][68];
    __shared__ float Bs[16][64];
    int t = threadIdx.x;
    int tx = t & 15, ty = t >> 4;
    int m0 = blockIdx.x * 64, n0 = blockIdx.y * 64;
    int am = t >> 2, ak = (t & 3) << 2;
    int bk = t >> 4, bnc = (t & 15) << 2;
    float acc[4][4] = {};
    for (int k0 = 0; k0 < K; k0 += 16) {
        float4 a4 = *(const float4*)&A[(size_t)(m0+am)*K + k0 + ak];
        if (A2) {
            float4 x4 = *(const float4*)&A2[(size_t)(m0+am)*K + k0 + ak];
            a4.x += x4.x; a4.y += x4.y; a4.z += x4.z; a4.w += x4.w;
        }
        As[ak+0][am] = a4.x; As[ak+1][am] = a4.y; As[ak+2][am] = a4.z; As[ak+3][am] = a4.w;
        *(float4*)&Bs[bk][bnc] = *(const float4*)&W[(size_t)(k0+bk)*N + n0 + bnc];
        __syncthreads();
        #pragma unroll
        for (int kk = 0; kk < 16; ++kk) {
            float4 av = *(const float4*)&As[kk][ty<<2];
            float4 bv = *(const float4*)&Bs[kk][tx<<2];
            acc[0][0] += av.x*bv.x; acc[0][1] += av.x*bv.y; acc[0][2] += av.x*bv.z; acc[0][3] += av.x*bv.w;
            acc[1][0] += av.y*bv.x; acc[1][1] += av.y*bv.y; acc[1][2] += av.y*bv.z; acc[1][3] += av.y*bv.w;
            acc[2][0] += av.z*bv.x; acc[2][1] += av.z*bv.y; acc[2][2] += av.z*bv.z; acc[2][3] += av.z*bv.w;
            acc[3][0] += av.w*bv.x; acc[3][1] += av.w*bv.y; acc[3][2] += av.w*bv.z; acc[3][3] += av.w*bv.w;
        }
        __syncthreads();
    }
    #pragma unroll
    for (int i = 0; i < 4; ++i) {
        int r = m0 + (ty<<2) + i;
        float4 o;
        float* po = (float*)&o;
        #pragma unroll
        for (int j = 0; j < 4; ++j) {
            int cidx = n0 + (tx<<2) + j;
            float v = (acc[i][j] + bias[cidx]) * scale;
            if (gelu_flag) v = 0.5f * v * (1.0f + erff(v * 0.70710678118654752f));
            po[j] = v;
        }
        size_t off = (size_t)r*N + n0 + (tx<<2);
        if (resid) {
            float4 rv = *(const float4*)&resid[off];
            o.x += rv.x; o.y += rv.y; o.z += rv.z; o.w += rv.w;
        }
        *(float4*)&out[off] = o;
    }
}

// ---------------- theta shift (RoPE-like), in place on q and k ----------------
__global__ void theta_kernel(float* __restrict__ q, float* __restrict__ k,
                             const float* __restrict__ sp, const float* __restrict__ cp)
{
    int idx = blockIdx.x * blockDim.x + threadIdx.x;   // Bn*Ln*Nh*16
    int p = idx & 15;
    int n = (idx >> 4) & 7;
    int rest = idx >> 7;
    int l = rest % Ln;
    int b = rest / Ln;
    if (b >= Bn) return;
    int d = p << 1;
    float c0 = cp[l*Dh + d], c1 = cp[l*Dh + d + 1];
    float s0 = sp[l*Dh + d], s1 = sp[l*Dh + d + 1];
    size_t off = ((size_t)(b*Ln + l)*Cn) + n*Dh + d;
    float q0 = q[off], q1 = q[off+1];
    q[off]   = q0*c0 - q1*s0;
    q[off+1] = q1*c1 + q0*s1;
    float k0 = k[off], k1 = k[off+1];
    k[off]   = k0*c0 - k1*s0;
    k[off+1] = k1*c1 + k0*s1;
}

__device__ __forceinline__ float bflo(unsigned int w){ return __uint_as_float(w << 16); }
__device__ __forceinline__ float bfhi(unsigned int w){ return __uint_as_float(w & 0xffff0000u); }

// ---------------- flash attention: 64 q-rows x 64 k-cols tiles, online softmax ----------------
// thread (ty=t>>4, tx=t&15): score rows ty*4+i, score cols tx+16*jj;
// output rows ty*4+i, dims (tx&7)*4..+3, partial over j-half jh=tx>>3.
__global__ __launch_bounds__(256, 4) void flash_kernel(
    const float* __restrict__ q, const float* __restrict__ k, const float* __restrict__ v,
    const float* __restrict__ mask, float* __restrict__ out)
{
    __shared__ float Qt[64][36];
    __shared__ float Kt[64][36];
    __shared__ float Vt[64][36];
    __shared__ __hip_bfloat16 Sb[64][72];
    int t = threadIdx.x;
    int tx = t & 15, ty = t >> 4;
    int jh = tx >> 3, dn = (tx & 7) << 2;
    int l0 = blockIdx.x << 6;
    int n = blockIdx.y;
    int b = blockIdx.z;
    {
        int row = t >> 2, col = (t & 3) << 3;
        const float* src = q + ((size_t)(b*Ln + l0 + row)*Cn + n*Dh + col);
        float4 v0 = *(const float4*)src;
        float4 v1 = *(const float4*)(src + 4);
        *(float4*)&Qt[row][col]   = v0;
        *(float4*)&Qt[row][col+4] = v1;
    }
    float m_[4], l_[4], O[4][4];
    #pragma unroll
    for (int i=0;i<4;++i){ m_[i] = -INFINITY; l_[i] = 0.f;
        #pragma unroll
        for(int d=0; d<4; ++d) O[i][d]=0.f; }
    const float* mbase = mask + (size_t)n*Ln*Ln;

    for (int m0 = 0; m0 < Ln; m0 += 64) {
        __syncthreads();
        {
            int row = t >> 2, col = (t & 3) << 3;
            const float* ks = k + ((size_t)(b*Ln + m0 + row)*Cn + n*Dh + col);
            const float* vs = v + ((size_t)(b*Ln + m0 + row)*Cn + n*Dh + col);
            float4 a0 = *(const float4*)ks;
            float4 a1 = *(const float4*)(ks+4);
            float4 b0 = *(const float4*)vs;
            float4 b1 = *(const float4*)(vs+4);
            *(float4*)&Kt[row][col]   = a0; *(float4*)&Kt[row][col+4] = a1;
            *(float4*)&Vt[row][col]   = b0; *(float4*)&Vt[row][col+4] = b1;
        }
        __syncthreads();
        // ---- scores: s[i][jj] = Q[ty*4+i] . K[tx+16jj] + mask ----
        float s[4][4];
        #pragma unroll
        for (int i=0;i<4;++i)
            #pragma unroll
            for (int jj=0;jj<4;++jj)
                s[i][jj] = mbase[(size_t)(l0 + (ty<<2) + i)*Ln + m0 + (jj<<4) + tx];
        #pragma unroll
        for (int d4 = 0; d4 < 8; ++d4) {
            float4 qv0 = *(const float4*)&Qt[(ty<<2)+0][d4<<2];
            float4 qv1 = *(const float4*)&Qt[(ty<<2)+1][d4<<2];
            float4 qv2 = *(const float4*)&Qt[(ty<<2)+2][d4<<2];
            float4 qv3 = *(const float4*)&Qt[(ty<<2)+3][d4<<2];
            float4 kv0 = *(const float4*)&Kt[tx +  0][d4<<2];
            float4 kv1 = *(const float4*)&Kt[tx + 16][d4<<2];
            float4 kv2 = *(const float4*)&Kt[tx + 32][d4<<2];
            float4 kv3 = *(const float4*)&Kt[tx + 48][d4<<2];
            s[0][0] += qv0.x*kv0.x + qv0.y*kv0.y + qv0.z*kv0.z + qv0.w*kv0.w;
            s[0][1] += qv0.x*kv1.x + qv0.y*kv1.y + qv0.z*kv1.z + qv0.w*kv1.w;
            s[0][2] += qv0.x*kv2.x + qv0.y*kv2.y + qv0.z*kv2.z + qv0.w*kv2.w;
            s[0][3] += qv0.x*kv3.x + qv0.y*kv3.y + qv0.z*kv3.z + qv0.w*kv3.w;
            s[1][0] += qv1.x*kv0.x + qv1.y*kv0.y + qv1.z*kv0.z + qv1.w*kv0.w;
            s[1][1] += qv1.x*kv1.x + qv1.y*kv1.y + qv1.z*kv1.z + qv1.w*kv1.w;
            s[1][2] += qv1.x*kv2.x + qv1.y*kv2.y + qv1.z*kv2.z + qv1.w*kv2.w;
            s[1][3] += qv1.x*kv3.x + qv1.y*kv3.y + qv1.z*kv3.z + qv1.w*kv3.w;
            s[2][0] += qv2.x*kv0.x + qv2.y*kv0.y + qv2.z*kv0.z + qv2.w*kv0.w;
            s[2][1] += qv2.x*kv1.x + qv2.y*kv1.y + qv2.z*kv1.z + qv2.w*kv1.w;
            s[2][2] += qv2.x*kv2.x + qv2.y*kv2.y + qv2.z*kv2.z + qv2.w*kv2.w;
            s[2][3] += qv2.x*kv3.x + qv2.y*kv3.y + qv2.z*kv3.z + qv2.w*kv3.w;
            s[3][0] += qv3.x*kv0.x + qv3.y*kv0.y + qv3.z*kv0.z + qv3.w*kv0.w;
            s[3][1] += qv3.x*kv1.x + qv3.y*kv1.y + qv3.z*kv1.z + qv3.w*kv1.w;
            s[3][2] += qv3.x*kv2.x + qv3.y*kv2.y + qv3.z*kv2.z + qv3.w*kv2.w;
            s[3][3] += qv3.x*kv3.x + qv3.y*kv3.y + qv3.z*kv3.z + qv3.w*kv3.w;
        }
        // ---- online softmax update (per row, reduced across 16 lanes) ----
        #pragma unroll
        for (int i=0;i<4;++i) {
            float tm = fmaxf(fmaxf(s[i][0], s[i][1]), fmaxf(s[i][2], s[i][3]));
            tm = fmaxf(tm, __shfl_xor(tm,1));
            tm = fmaxf(tm, __shfl_xor(tm,2));
            tm = fmaxf(tm, __shfl_xor(tm,4));
            tm = fmaxf(tm, __shfl_xor(tm,8));
            float nm = fmaxf(m_[i], tm);
            float al = __expf(m_[i] - nm);
            m_[i] = nm;
            float ps = 0.f;
            #pragma unroll
            for (int jj=0;jj<4;++jj) {
                float p = __expf(s[i][jj] - nm);
                ps += p;
                Sb[(ty<<2)+i][(jj<<4)+tx] = __float2bfloat16(p);
            }
            ps += __shfl_xor(ps,1); ps += __shfl_xor(ps,2);
            ps += __shfl_xor(ps,4); ps += __shfl_xor(ps,8);
            l_[i] = l_[i]*al + ps;
            #pragma unroll
            for (int d=0; d<4; ++d) O[i][d] *= al;
        }
        __syncthreads();
        // ---- PV: O[i][dn..] += sum_{j in half} P[i][j] * V[j][dn..] ----
        #pragma unroll
        for (int j8 = 0; j8 < 4; ++j8) {
            int jb = (jh<<5) + (j8<<3);
            float4 vv0 = *(const float4*)&Vt[jb+0][dn];
            float4 vv1 = *(const float4*)&Vt[jb+1][dn];
            float4 vv2 = *(const float4*)&Vt[jb+2][dn];
            float4 vv3 = *(const float4*)&Vt[jb+3][dn];
            float4 vv4 = *(const float4*)&Vt[jb+4][dn];
            float4 vv5 = *(const float4*)&Vt[jb+5][dn];
            float4 vv6 = *(const float4*)&Vt[jb+6][dn];
            float4 vv7 = *(const float4*)&Vt[jb+7][dn];
            #pragma unroll
            for (int i=0;i<4;++i) {
                uint4 pw = *(const uint4*)((const unsigned short*)(&Sb[(ty<<2)+i][0]) + jb);
                float p0 = bflo(pw.x), p1 = bfhi(pw.x);
                float p2 = bflo(pw.y), p3 = bfhi(pw.y);
                float p4 = bflo(pw.z), p5 = bfhi(pw.z);
                float p6 = bflo(pw.w), p7 = bfhi(pw.w);
                O[i][0] += p0*vv0.x + p1*vv1.x + p2*vv2.x + p3*vv3.x + p4*vv4.x + p5*vv5.x + p6*vv6.x + p7*vv7.x;
                O[i][1] += p0*vv0.y + p1*vv1.y + p2*vv2.y + p3*vv3.y + p4*vv4.y + p5*vv5.y + p6*vv6.y + p7*vv7.y;
                O[i][2] += p0*vv0.z + p1*vv1.z + p2*vv2.z + p3*vv3.z + p4*vv4.z + p5*vv5.z + p6*vv6.z + p7*vv7.z;
                O[i][3] += p0*vv0.w + p1*vv1.w + p2*vv2.w + p3*vv3.w + p4*vv4.w + p5*vv5.w + p6*vv6.w + p7*vv7.w;
            }
        }
    }
    // combine j-halves via LDS (reuse Qt), normalize, store
    __syncthreads();
    if (jh == 1) {
        #pragma unroll
        for (int i=0;i<4;++i)
            *(float4*)&Qt[(ty<<2)+i][dn] = make_float4(O[i][0],O[i][1],O[i][2],O[i][3]);
    }
    __syncthreads();
    if (jh == 0) {
        #pragma unroll
        for (int i=0;i<4;++i) {
            float inv = 1.0f / l_[i];
            float4 o1 = *(const float4*)&Qt[(ty<<2)+i][dn];
            float4 o;
            o.x = (O[i][0]+o1.x)*inv;
            o.y = (O[i][1]+o1.y)*inv;
            o.z = (O[i][2]+o1.z)*inv;
            o.w = (O[i][3]+o1.w)*inv;
            *(float4*)&out[((size_t)(b*Ln + l0 + (ty<<2) + i)*Cn + n*Dh + dn)] = o;
        }
    }
}

extern "C" void kernel_launch(void* const* d_in, const int* in_sizes, int n_in,
                              void* d_out, int out_size, void* d_ws, size_t ws_size,
                              hipStream_t stream) {
    const float* x     = (const float*)d_in[0];
    const float* sinp  = (const float*)d_in[1];
    const float* cosp  = (const float*)d_in[2];
    const float* mask  = (const float*)d_in[3];
    const float* pos_w = (const float*)d_in[4];
    const float* pos_b = (const float*)d_in[5];
    const float* ln1_g = (const float*)d_in[6];
    const float* ln1_b = (const float*)d_in[7];
    const float* wq = (const float*)d_in[8];
    const float* bq = (const float*)d_in[9];
    const float* wk = (const float*)d_in[10];
    const float* bk = (const float*)d_in[11];
    const float* wv = (const float*)d_in[12];
    const float* bv = (const float*)d_in[13];
    const float* lepe_w = (const float*)d_in[14];
    const float* lepe_b = (const float*)d_in[15];
    const float* wo = (const float*)d_in[16];
    const float* bo = (const float*)d_in[17];
    const float* ln2_g = (const float*)d_in[18];
    const float* ln2_b = (const float*)d_in[19];
    const float* w1 = (const float*)d_in[20];
    const float* b1 = (const float*)d_in[21];
    const float* ffn_w = (const float*)d_in[22];
    const float* ffn_b = (const float*)d_in[23];
    const float* w2 = (const float*)d_in[24];
    const float* b2 = (const float*)d_in[25];

    float* ws = (float*)d_ws;
    const size_t MC = (size_t)Mrows*Cn;
    // layout (MC units): 0 xbuf | 1 ybuf/att | 2 q | 3 k | 4 v | 5 lepe | 6 x2 | 7 zbuf | 8..12 z2
    // z1 reuses 0..4 (xbuf/att/q/k all dead by then)
    float* xbuf = ws;
    float* ybuf = ws + MC;
    float* qbuf = ws + 2*MC;
    float* kbuf = ws + 3*MC;
    float* vbuf = ws + 4*MC;
    float* lepe = ws + 5*MC;
    float* att  = ybuf;          // reuse: ybuf dead after qkv GEMMs
    float* x2   = ws + 6*MC;
    float* zbuf = ws + 7*MC;
    float* z1   = ws;            // reuse 0..4MC (needs Mrows*Fn = 4*MC)
    float* z2   = ws + 8*MC;     // 8..12MC
    float* outp = (float*)d_out;

    int totalC = Mrows*Cn/4;
    int totalF = Mrows*Fn/4;
    dim3 gg(Mrows/64, Cn/64);
    dim3 g1(Mrows/64, Fn/64);
    dim3 fg(Ln/64, Nh, Bn);

    // 1. x = x + dwconv3x3(x)
    dwconv_kernel<<<(totalC+255)/256, 256, 0, stream>>>(x, pos_w, pos_b, xbuf, Cn, 3, 1, 1);
    // 2. y = LN1(x)
    ln_kernel<<<Mrows, 256, 0, stream>>>(xbuf, ln1_g, ln1_b, ybuf);
    // 3. q,k,v
    gemm_kernel<<<gg, 256, 0, stream>>>(ybuf, nullptr, wq, bq, nullptr, qbuf, Mrows, Cn, Cn, 1.0f, 0);
    gemm_kernel<<<gg, 256, 0, stream>>>(ybuf, nullptr, wk, bk, nullptr, kbuf, Mrows, Cn, Cn, SCALING_K, 0);
    gemm_kernel<<<gg, 256, 0, stream>>>(ybuf, nullptr, wv, bv, nullptr, vbuf, Mrows, Cn, Cn, 1.0f, 0);
    // 4. theta shift q,k in place
    theta_kernel<<<(Bn*Ln*Nh*16)/256, 256, 0, stream>>>(qbuf, kbuf, sinp, cosp);
    // 5. lepe = dwconv5x5(v)
    dwconv_kernel<<<(totalC+255)/256, 256, 0, stream>>>(vbuf, lepe_w, lepe_b, lepe, Cn, 5, 2, 0);
    // 6. attention
    flash_kernel<<<fg, 256, 0, stream>>>(qbuf, kbuf, vbuf, mask, att);
    // 7. x2 = x + (att + lepe) @ wo + bo
    gemm_kernel<<<gg, 256, 0, stream>>>(att, lepe, wo, bo, xbuf, x2, Mrows, Cn, Cn, 1.0f, 0);
    // 8. z = LN2(x2)
    ln_kernel<<<Mrows, 256, 0, stream>>>(x2, ln2_g, ln2_b, zbuf);
    // 9. z1 = gelu(z @ w1 + b1)
    gemm_kernel<<<g1, 256, 0, stream>>>(zbuf, nullptr, w1, b1, nullptr, z1, Mrows, Cn, Fn, 1.0f, 1);
    // 10. z2 = z1 + dwconv3x3(z1)
    dwconv_kernel<<<(totalF+255)/256, 256, 0, stream>>>(z1, ffn_w, ffn_b, z2, Fn, 3, 1, 1);
    // 11. out = x2 + z2 @ w2 + b2
    gemm_kernel<<<gg, 256, 0, stream>>>(z2, nullptr, w2, b2, x2, outp, Mrows, Fn, Cn, 1.0f, 0);
}

// Round 2
// 812.294 us; speedup vs baseline: 4.3529x; 4.3529x over previous
//
#include <hip/hip_runtime.h>
#include <hip/hip_bf16.h>
#include <math.h>

#define Bn 2
#define Hn 56
#define Wn 56
#define Cn 256
#define Nh 8
#define Dh 32
#define Fn 1024
#define Ln (Hn*Wn)          // 3136
#define Mrows (Bn*Ln)       // 6272
#define SCALING_K 0.17677669529663687f   // 32^-0.5

typedef __attribute__((ext_vector_type(4))) float f32x4;
typedef __attribute__((ext_vector_type(8))) short s16x8;
typedef unsigned short ushort_t;

__device__ __forceinline__ ushort_t f2bf(float f) {
    __hip_bfloat16 h = __float2bfloat16(f);
    return *reinterpret_cast<ushort_t*>(&h);
}

// ---------------- depthwise conv (3x3 or 5x5), optional residual add ----------------
__global__ void dwconv_kernel(const float* __restrict__ in, const float* __restrict__ wgt,
                              const float* __restrict__ bias, float* __restrict__ out,
                              int C, int KS, int pad, int addin)
{
    int idx = blockIdx.x * blockDim.x + threadIdx.x;
    int c4 = C >> 2;
    int c = (idx % c4) << 2;
    int rest = idx / c4;
    int w = rest % Wn; rest /= Wn;
    int h = rest % Hn;
    int b = rest / Hn;
    if (b >= Bn) return;
    float4 acc = *(const float4*)&bias[c];
    for (int dh = 0; dh < KS; ++dh) {
        int hh = h + dh - pad;
        if (hh < 0 || hh >= Hn) continue;
        for (int dw = 0; dw < KS; ++dw) {
            int ww = w + dw - pad;
            if (ww < 0 || ww >= Wn) continue;
            float4 xv = *(const float4*)&in[(((size_t)b*Hn + hh)*Wn + ww)*C + c];
            float4 wv = *(const float4*)&wgt[(size_t)(dh*KS + dw)*C + c];
            acc.x += xv.x*wv.x; acc.y += xv.y*wv.y; acc.z += xv.z*wv.z; acc.w += xv.w*wv.w;
        }
    }
    size_t o = (((size_t)b*Hn + h)*Wn + w)*C + c;
    if (addin) {
        float4 xv = *(const float4*)&in[o];
        acc.x += xv.x; acc.y += xv.y; acc.z += xv.z; acc.w += xv.w;
    }
    *(float4*)&out[o] = acc;
}

// ---------------- layernorm over C=256, one block per row ----------------
__global__ __launch_bounds__(256) void ln_kernel(const float* __restrict__ in,
    const float* __restrict__ g, const float* __restrict__ b, float* __restrict__ out)
{
    int row = blockIdx.x;
    int t = threadIdx.x;
    float v = in[(size_t)row*Cn + t];
    float s1 = v, s2 = v*v;
    for (int m = 1; m < 64; m <<= 1) {
        s1 += __shfl_xor(s1, m);
        s2 += __shfl_xor(s2, m);
    }
    __shared__ float w1s[4], w2s[4];
    if ((t & 63) == 0) { w1s[t>>6] = s1; w2s[t>>6] = s2; }
    __syncthreads();
    s1 = w1s[0]+w1s[1]+w1s[2]+w1s[3];
    s2 = w2s[0]+w2s[1]+w2s[2]+w2s[3];
    float mean = s1 * (1.0f/Cn);
    float var  = s2 * (1.0f/Cn) - mean*mean;
    float r = rsqrtf(var + 1e-6f);
    out[(size_t)row*Cn + t] = (v - mean) * r * g[t] + b[t];
}

// ---------------- fp32 tiled GEMM: out = epi(((A[+A2]) @ W + bias)*scale) [+resid] ----------------
__global__ __launch_bounds__(256) void gemm_kernel(
    const float* __restrict__ A, const float* __restrict__ A2,
    const float* __restrict__ W, const float* __restrict__ bias,
    const float* __restrict__ resid, float* __restrict__ out,
    int M, int K, int N, float scale, int gelu_flag)
{
    __shared__ float As[16][68];
    __shared__ float Bs[16][64];
    int t = threadIdx.x;
    int tx = t & 15, ty = t >> 4;
    int m0 = blockIdx.x * 64, n0 = blockIdx.y * 64;
    int am = t >> 2, ak = (t & 3) << 2;
    int bk = t >> 4, bnc = (t & 15) << 2;
    float acc[4][4] = {};
    for (int k0 = 0; k0 < K; k0 += 16) {
        float4 a4 = *(const float4*)&A[(size_t)(m0+am)*K + k0 + ak];
        if (A2) {
            float4 x4 = *(const float4*)&A2[(size_t)(m0+am)*K + k0 + ak];
            a4.x += x4.x; a4.y += x4.y; a4.z += x4.z; a4.w += x4.w;
        }
        As[ak+0][am] = a4.x; As[ak+1][am] = a4.y; As[ak+2][am] = a4.z; As[ak+3][am] = a4.w;
        *(float4*)&Bs[bk][bnc] = *(const float4*)&W[(size_t)(k0+bk)*N + n0 + bnc];
        __syncthreads();
        #pragma unroll
        for (int kk = 0; kk < 16; ++kk) {
            float4 av = *(const float4*)&As[kk][ty<<2];
            float4 bv = *(const float4*)&Bs[kk][tx<<2];
            acc[0][0] += av.x*bv.x; acc[0][1] += av.x*bv.y; acc[0][2] += av.x*bv.z; acc[0][3] += av.x*bv.w;
            acc[1][0] += av.y*bv.x; acc[1][1] += av.y*bv.y; acc[1][2] += av.y*bv.z; acc[1][3] += av.y*bv.w;
            acc[2][0] += av.z*bv.x; acc[2][1] += av.z*bv.y; acc[2][2] += av.z*bv.z; acc[2][3] += av.z*bv.w;
            acc[3][0] += av.w*bv.x; acc[3][1] += av.w*bv.y; acc[3][2] += av.w*bv.z; acc[3][3] += av.w*bv.w;
        }
        __syncthreads();
    }
    #pragma unroll
    for (int i = 0; i < 4; ++i) {
        int r = m0 + (ty<<2) + i;
        float4 o;
        float* po = (float*)&o;
        #pragma unroll
        for (int j = 0; j < 4; ++j) {
            int cidx = n0 + (tx<<2) + j;
            float v = (acc[i][j] + bias[cidx]) * scale;
            if (gelu_flag) v = 0.5f * v * (1.0f + erff(v * 0.70710678118654752f));
            po[j] = v;
        }
        size_t off = (size_t)r*N + n0 + (tx<<2);
        if (resid) {
            float4 rv = *(const float4*)&resid[off];
            o.x += rv.x; o.y += rv.y; o.z += rv.z; o.w += rv.w;
        }
        *(float4*)&out[off] = o;
    }
}

// ---------------- pack: theta-shift + cast to bf16, head-major; V transposed ----------------
// qb,kb: [b][n][l][32] bf16 ; vbT: [b][n][32][l] bf16
__global__ __launch_bounds__(256) void pack_qkv(
    const float* __restrict__ q, const float* __restrict__ k, const float* __restrict__ v,
    const float* __restrict__ sp, const float* __restrict__ cp,
    ushort_t* __restrict__ qb, ushort_t* __restrict__ kb, ushort_t* __restrict__ vbT)
{
    __shared__ __align__(16) ushort_t Vl[64][40];
    int t = threadIdx.x;
    int l0 = blockIdx.x << 6;
    int n = blockIdx.y;
    int b = blockIdx.z;
    {
        int ll = t >> 2, dc = (t & 3) << 3;
        int l = l0 + ll;
        size_t gbase = ((size_t)(b*Ln + l))*Cn + n*Dh + dc;
        float qx[8], kx[8], vx[8], sv[8], cv[8];
        *(float4*)&qx[0] = *(const float4*)&q[gbase];
        *(float4*)&qx[4] = *(const float4*)&q[gbase+4];
        *(float4*)&kx[0] = *(const float4*)&k[gbase];
        *(float4*)&kx[4] = *(const float4*)&k[gbase+4];
        *(float4*)&vx[0] = *(const float4*)&v[gbase];
        *(float4*)&vx[4] = *(const float4*)&v[gbase+4];
        size_t scb = (size_t)l*Dh + dc;
        *(float4*)&sv[0] = *(const float4*)&sp[scb];
        *(float4*)&sv[4] = *(const float4*)&sp[scb+4];
        *(float4*)&cv[0] = *(const float4*)&cp[scb];
        *(float4*)&cv[4] = *(const float4*)&cp[scb+4];
        ushort_t qo[8], ko[8], vo[8];
        #pragma unroll
        for (int j = 0; j < 8; j += 2) {
            float q0 = qx[j]*cv[j] - qx[j+1]*sv[j];
            float q1 = qx[j+1]*cv[j+1] + qx[j]*sv[j+1];
            float k0 = kx[j]*cv[j] - kx[j+1]*sv[j];
            float k1 = kx[j+1]*cv[j+1] + kx[j]*sv[j+1];
            qo[j] = f2bf(q0); qo[j+1] = f2bf(q1);
            ko[j] = f2bf(k0); ko[j+1] = f2bf(k1);
            vo[j] = f2bf(vx[j]); vo[j+1] = f2bf(vx[j+1]);
        }
        size_t hbase = ((size_t)((b*Nh + n)*Ln + l))*Dh + dc;
        *(uint4*)&qb[hbase] = *(uint4*)qo;
        *(uint4*)&kb[hbase] = *(uint4*)ko;
        *(uint4*)&Vl[ll][dc] = *(uint4*)vo;
    }
    __syncthreads();
    {
        int d = t >> 3, lc = (t & 7) << 3;
        ushort_t tmp[8];
        #pragma unroll
        for (int i = 0; i < 8; ++i) tmp[i] = Vl[lc + i][d];
        size_t tbase = ((size_t)((b*Nh + n)*Dh + d))*Ln + l0 + lc;
        *(uint4*)&vbT[tbase] = *(uint4*)tmp;
    }
}

// ---------------- MFMA flash attention ----------------
// block = 256 threads = 4 waves; block handles 64 q-rows of one (b,n).
// wave w owns q-rows l0+w*16 .. +15. mfma_f32_16x16x32_bf16:
//   A[m=lane&15][k=quad*8+j], B[n=lane&15][k=quad*8+j], C/D: col=lane&15, row=quad*4+reg.
__global__ __launch_bounds__(256) void flash_mfma(
    const ushort_t* __restrict__ qb, const ushort_t* __restrict__ kb,
    const ushort_t* __restrict__ vbT, const float* __restrict__ mask,
    float* __restrict__ out)
{
    __shared__ __align__(16) ushort_t Kt[64][40];   // [key][d]   pad->2-way max
    __shared__ __align__(16) ushort_t Vt[32][72];   // [d][key]
    __shared__ __align__(16) ushort_t Ps[4][16][72];// per-wave P tile [row][col]
    int t = threadIdx.x;
    int wid = t >> 6, lane = t & 63;
    int l16 = lane & 15, quad = lane >> 4;
    int l0 = blockIdx.x << 6;
    int n = blockIdx.y;
    int b = blockIdx.z;

    const ushort_t* qbp = qb + ((size_t)(b*Nh + n))*Ln*Dh;
    const ushort_t* kbp = kb + ((size_t)(b*Nh + n))*Ln*Dh;
    const ushort_t* vtp = vbT + ((size_t)(b*Nh + n))*Dh*Ln;
    // Q fragment (persistent): rows l0+wid*16+l16, k = quad*8..+7
    s16x8 qfrag = *(const s16x8*)(qbp + (size_t)(l0 + wid*16 + l16)*Dh + quad*8);
    // mask row base for this lane's 4 rows (add r*Ln per reg)
    const float* mbase = mask + (size_t)n*Ln*Ln + (size_t)(l0 + wid*16 + quad*4)*Ln;

    f32x4 O0 = {0.f,0.f,0.f,0.f}, O1 = {0.f,0.f,0.f,0.f};
    float m_[4], l_[4];
    #pragma unroll
    for (int r = 0; r < 4; ++r) { m_[r] = -INFINITY; l_[r] = 0.f; }

    int srow = t >> 2, scol = (t & 3) << 3;   // K staging: 64 rows x 32 d
    int vrow = t >> 3, vcol = (t & 7) << 3;   // Vt staging: 32 rows x 64 key

    for (int m0 = 0; m0 < Ln; m0 += 64) {
        __syncthreads();
        *(uint4*)&Kt[srow][scol] = *(const uint4*)(kbp + (size_t)(m0 + srow)*Dh + scol);
        *(uint4*)&Vt[vrow][vcol] = *(const uint4*)(vtp + (size_t)vrow*Ln + m0 + vcol);
        __syncthreads();

        // mask as MFMA C operand
        f32x4 c0, c1, c2, c3;
        #pragma unroll
        for (int r = 0; r < 4; ++r) {
            const float* mr = mbase + (size_t)r*Ln + m0 + l16;
            c0[r] = mr[0]; c1[r] = mr[16]; c2[r] = mr[32]; c3[r] = mr[48];
        }
        f32x4 S[4];
        {
            s16x8 kf0 = *(const s16x8*)&Kt[ 0 + l16][quad*8];
            s16x8 kf1 = *(const s16x8*)&Kt[16 + l16][quad*8];
            s16x8 kf2 = *(const s16x8*)&Kt[32 + l16][quad*8];
            s16x8 kf3 = *(const s16x8*)&Kt[48 + l16][quad*8];
            S[0] = __builtin_amdgcn_mfma_f32_16x16x32_bf16(qfrag, kf0, c0, 0, 0, 0);
            S[1] = __builtin_amdgcn_mfma_f32_16x16x32_bf16(qfrag, kf1, c1, 0, 0, 0);
            S[2] = __builtin_amdgcn_mfma_f32_16x16x32_bf16(qfrag, kf2, c2, 0, 0, 0);
            S[3] = __builtin_amdgcn_mfma_f32_16x16x32_bf16(qfrag, kf3, c3, 0, 0, 0);
        }
        // online softmax per row (rows quad*4+r; cols spread over 16 lanes of quad)
        #pragma unroll
        for (int r = 0; r < 4; ++r) {
            float tm = fmaxf(fmaxf(S[0][r], S[1][r]), fmaxf(S[2][r], S[3][r]));
            tm = fmaxf(tm, __shfl_xor(tm, 1));
            tm = fmaxf(tm, __shfl_xor(tm, 2));
            tm = fmaxf(tm, __shfl_xor(tm, 4));
            tm = fmaxf(tm, __shfl_xor(tm, 8));
            float nm = fmaxf(m_[r], tm);
            float al = __expf(m_[r] - nm);
            m_[r] = nm;
            float p0 = __expf(S[0][r] - nm);
            float p1 = __expf(S[1][r] - nm);
            float p2 = __expf(S[2][r] - nm);
            float p3 = __expf(S[3][r] - nm);
            float ps = p0 + p1 + p2 + p3;
            ps += __shfl_xor(ps, 1); ps += __shfl_xor(ps, 2);
            ps += __shfl_xor(ps, 4); ps += __shfl_xor(ps, 8);
            l_[r] = l_[r]*al + ps;
            O0[r] *= al; O1[r] *= al;
            int rr = quad*4 + r;
            Ps[wid][rr][ 0 + l16] = f2bf(p0);
            Ps[wid][rr][16 + l16] = f2bf(p1);
            Ps[wid][rr][32 + l16] = f2bf(p2);
            Ps[wid][rr][48 + l16] = f2bf(p3);
        }
        // PV: A = P (A-layout read from own wave's LDS region; DS ops in-order per wave),
        //     B = Vt rows (d), k = key
        #pragma unroll
        for (int kc = 0; kc < 2; ++kc) {
            s16x8 pf  = *(const s16x8*)&Ps[wid][l16][kc*32 + quad*8];
            s16x8 vf0 = *(const s16x8*)&Vt[ 0 + l16][kc*32 + quad*8];
            s16x8 vf1 = *(const s16x8*)&Vt[16 + l16][kc*32 + quad*8];
            O0 = __builtin_amdgcn_mfma_f32_16x16x32_bf16(pf, vf0, O0, 0, 0, 0);
            O1 = __builtin_amdgcn_mfma_f32_16x16x32_bf16(pf, vf1, O1, 0, 0, 0);
        }
    }
    // epilogue: normalize, store to att buffer [Mrows][Cn] at head offset
    #pragma unroll
    for (int r = 0; r < 4; ++r) {
        float inv = 1.0f / l_[r];
        size_t row = (size_t)(b*Ln + l0 + wid*16 + quad*4 + r)*Cn + n*Dh;
        out[row + l16]      = O0[r] * inv;
        out[row + 16 + l16] = O1[r] * inv;
    }
}

extern "C" void kernel_launch(void* const* d_in, const int* in_sizes, int n_in,
                              void* d_out, int out_size, void* d_ws, size_t ws_size,
                              hipStream_t stream) {
    const float* x     = (const float*)d_in[0];
    const float* sinp  = (const float*)d_in[1];
    const float* cosp  = (const float*)d_in[2];
    const float* mask  = (const float*)d_in[3];
    const float* pos_w = (const float*)d_in[4];
    const float* pos_b = (const float*)d_in[5];
    const float* ln1_g = (const float*)d_in[6];
    const float* ln1_b = (const float*)d_in[7];
    const float* wq = (const float*)d_in[8];
    const float* bq = (const float*)d_in[9];
    const float* wk = (const float*)d_in[10];
    const float* bk = (const float*)d_in[11];
    const float* wv = (const float*)d_in[12];
    const float* bv = (const float*)d_in[13];
    const float* lepe_w = (const float*)d_in[14];
    const float* lepe_b = (const float*)d_in[15];
    const float* wo = (const float*)d_in[16];
    const float* bo = (const float*)d_in[17];
    const float* ln2_g = (const float*)d_in[18];
    const float* ln2_b = (const float*)d_in[19];
    const float* w1 = (const float*)d_in[20];
    const float* b1 = (const float*)d_in[21];
    const float* ffn_w = (const float*)d_in[22];
    const float* ffn_b = (const float*)d_in[23];
    const float* w2 = (const float*)d_in[24];
    const float* b2 = (const float*)d_in[25];

    float* ws = (float*)d_ws;
    const size_t MC = (size_t)Mrows*Cn;
    // fp32 regions (MC units): 0 xbuf | 1 ybuf/att | 2 q | 3 k | 4 v | 5 lepe | 6 x2 | 7 zbuf | 8..12 z2
    // z1 reuses 0..4MC. bf16 qb/kb/vbT live in regions 7/8/9 (time-disjoint with zbuf/z2).
    float* xbuf = ws;
    float* ybuf = ws + MC;
    float* qbuf = ws + 2*MC;
    float* kbuf = ws + 3*MC;
    float* vbuf = ws + 4*MC;
    float* lepe = ws + 5*MC;
    float* att  = ybuf;
    float* x2   = ws + 6*MC;
    float* zbuf = ws + 7*MC;
    float* z1   = ws;
    float* z2   = ws + 8*MC;
    ushort_t* qb  = (ushort_t*)(ws + 7*MC);   // 3.2MB, dead before zbuf written
    ushort_t* kb  = (ushort_t*)(ws + 8*MC);   // dead before z2 written
    ushort_t* vbT = (ushort_t*)(ws + 9*MC);
    float* outp = (float*)d_out;

    int totalC = Mrows*Cn/4;
    int totalF = Mrows*Fn/4;
    dim3 gg(Mrows/64, Cn/64);
    dim3 g1(Mrows/64, Fn/64);
    dim3 fg(Ln/64, Nh, Bn);

    // 1. x = x + dwconv3x3(x)
    dwconv_kernel<<<(totalC+255)/256, 256, 0, stream>>>(x, pos_w, pos_b, xbuf, Cn, 3, 1, 1);
    // 2. y = LN1(x)
    ln_kernel<<<Mrows, 256, 0, stream>>>(xbuf, ln1_g, ln1_b, ybuf);
    // 3. q,k,v
    gemm_kernel<<<gg, 256, 0, stream>>>(ybuf, nullptr, wq, bq, nullptr, qbuf, Mrows, Cn, Cn, 1.0f, 0);
    gemm_kernel<<<gg, 256, 0, stream>>>(ybuf, nullptr, wk, bk, nullptr, kbuf, Mrows, Cn, Cn, SCALING_K, 0);
    gemm_kernel<<<gg, 256, 0, stream>>>(ybuf, nullptr, wv, bv, nullptr, vbuf, Mrows, Cn, Cn, 1.0f, 0);
    // 4. pack: theta shift + bf16 head-major + V transpose
    pack_qkv<<<fg, 256, 0, stream>>>(qbuf, kbuf, vbuf, sinp, cosp, qb, kb, vbT);
    // 5. lepe = dwconv5x5(v)
    dwconv_kernel<<<(totalC+255)/256, 256, 0, stream>>>(vbuf, lepe_w, lepe_b, lepe, Cn, 5, 2, 0);
    // 6. attention (MFMA)
    flash_mfma<<<fg, 256, 0, stream>>>(qb, kb, vbT, mask, att);
    // 7. x2 = x + (att + lepe) @ wo + bo
    gemm_kernel<<<gg, 256, 0, stream>>>(att, lepe, wo, bo, xbuf, x2, Mrows, Cn, Cn, 1.0f, 0);
    // 8. z = LN2(x2)
    ln_kernel<<<Mrows, 256, 0, stream>>>(x2, ln2_g, ln2_b, zbuf);
    // 9. z1 = gelu(z @ w1 + b1)
    gemm_kernel<<<g1, 256, 0, stream>>>(zbuf, nullptr, w1, b1, nullptr, z1, Mrows, Cn, Fn, 1.0f, 1);
    // 10. z2 = z1 + dwconv3x3(z1)
    dwconv_kernel<<<(totalF+255)/256, 256, 0, stream>>>(z1, ffn_w, ffn_b, z2, Fn, 3, 1, 1);
    // 11. out = x2 + z2 @ w2 + b2
    gemm_kernel<<<gg, 256, 0, stream>>>(z2, nullptr, w2, b2, x2, outp, Mrows, Fn, Cn, 1.0f, 0);
}

// Round 3
// 683.529 us; speedup vs baseline: 5.1729x; 1.1884x over previous
//
#include <hip/hip_runtime.h>
#include <hip/hip_bf16.h>
#include <math.h>

#define Bn 2
#define Hn 56
#define Wn 56
#define Cn 256
#define Nh 8
#define Dh 32
#define Fn 1024
#define Ln (Hn*Wn)          // 3136
#define Mrows (Bn*Ln)       // 6272
#define SCALING_K 0.17677669529663687f   // 32^-0.5

typedef __attribute__((ext_vector_type(4))) float f32x4;
typedef __attribute__((ext_vector_type(8))) short s16x8;
typedef unsigned short ushort_t;

__device__ __forceinline__ ushort_t f2bf(float f) {
    __hip_bfloat16 h = __float2bfloat16(f);
    return *reinterpret_cast<ushort_t*>(&h);
}

// ---------------- depthwise conv (3x3 or 5x5), optional residual add ----------------
__global__ void dwconv_kernel(const float* __restrict__ in, const float* __restrict__ wgt,
                              const float* __restrict__ bias, float* __restrict__ out,
                              int C, int inld, int outld, int KS, int pad, int addin)
{
    int idx = blockIdx.x * blockDim.x + threadIdx.x;
    int c4 = C >> 2;
    int c = (idx % c4) << 2;
    int rest = idx / c4;
    int w = rest % Wn; rest /= Wn;
    int h = rest % Hn;
    int b = rest / Hn;
    if (b >= Bn) return;
    float4 acc = *(const float4*)&bias[c];
    for (int dh = 0; dh < KS; ++dh) {
        int hh = h + dh - pad;
        if (hh < 0 || hh >= Hn) continue;
        for (int dw = 0; dw < KS; ++dw) {
            int ww = w + dw - pad;
            if (ww < 0 || ww >= Wn) continue;
            float4 xv = *(const float4*)&in[(((size_t)b*Hn + hh)*Wn + ww)*inld + c];
            float4 wv = *(const float4*)&wgt[(size_t)(dh*KS + dw)*C + c];
            acc.x += xv.x*wv.x; acc.y += xv.y*wv.y; acc.z += xv.z*wv.z; acc.w += xv.w*wv.w;
        }
    }
    size_t oidx = (((size_t)b*Hn + h)*Wn + w);
    if (addin) {
        float4 xv = *(const float4*)&in[oidx*inld + c];
        acc.x += xv.x; acc.y += xv.y; acc.z += xv.z; acc.w += xv.w;
    }
    *(float4*)&out[oidx*outld + c] = acc;
}

// ---------------- layernorm over C=256, one block per row ----------------
__global__ __launch_bounds__(256) void ln_kernel(const float* __restrict__ in,
    const float* __restrict__ g, const float* __restrict__ b, float* __restrict__ out)
{
    int row = blockIdx.x;
    int t = threadIdx.x;
    float v = in[(size_t)row*Cn + t];
    float s1 = v, s2 = v*v;
    for (int m = 1; m < 64; m <<= 1) {
        s1 += __shfl_xor(s1, m);
        s2 += __shfl_xor(s2, m);
    }
    __shared__ float w1s[4], w2s[4];
    if ((t & 63) == 0) { w1s[t>>6] = s1; w2s[t>>6] = s2; }
    __syncthreads();
    s1 = w1s[0]+w1s[1]+w1s[2]+w1s[3];
    s2 = w2s[0]+w2s[1]+w2s[2]+w2s[3];
    float mean = s1 * (1.0f/Cn);
    float var  = s2 * (1.0f/Cn) - mean*mean;
    float r = rsqrtf(var + 1e-6f);
    out[(size_t)row*Cn + t] = (v - mean) * r * g[t] + b[t];
}

// ---------------- weight prep: transpose + bf16 cast; concat qkv with k-scaling ----------------
__global__ void prep_weights(const float* __restrict__ wq, const float* __restrict__ bq,
                             const float* __restrict__ wk, const float* __restrict__ bk,
                             const float* __restrict__ wv, const float* __restrict__ bv,
                             const float* __restrict__ wo, const float* __restrict__ w1,
                             const float* __restrict__ w2,
                             ushort_t* __restrict__ wqkvT, float* __restrict__ bqkv,
                             ushort_t* __restrict__ woT, ushort_t* __restrict__ w1T,
                             ushort_t* __restrict__ w2T)
{
    int idx = blockIdx.x * 256 + threadIdx.x;
    if (idx < 196608) {                       // wqkvT [768][256]
        int j = idx >> 8, k = idx & 255;
        float v;
        if (j < 256)      v = wq[k*256 + j];
        else if (j < 512) v = wk[k*256 + (j-256)] * SCALING_K;
        else              v = wv[k*256 + (j-512)];
        wqkvT[idx] = f2bf(v);
    } else if (idx < 262144) {                // woT [256][256]
        int r = idx - 196608;
        int j = r >> 8, k = r & 255;
        woT[r] = f2bf(wo[k*256 + j]);
    } else if (idx < 524288) {                // w1T [1024][256]
        int r = idx - 262144;
        int j = r >> 8, k = r & 255;
        w1T[r] = f2bf(w1[k*1024 + j]);
    } else if (idx < 786432) {                // w2T [256][1024]
        int r = idx - 524288;
        int j = r >> 10, k = r & 1023;
        w2T[r] = f2bf(w2[k*256 + j]);
    } else if (idx < 787200) {                // bqkv [768]
        int j = idx - 786432;
        bqkv[j] = (j < 256) ? bq[j] : (j < 512 ? bk[j-256]*SCALING_K : bv[j-512]);
    }
}

// ---------------- bf16 MFMA GEMM: out = epi((A[+A2]) @ BT^T + bias) [+resid] ----------------
// tile 64(M)x64(N), BK=32, 256 thr / 4 waves; wave w: rows 16w..16w+15, all 64 cols.
// grid.x = N/64 (fast: A-tile L2 reuse), grid.y = M/64.
__global__ __launch_bounds__(256) void gemm_bf16(
    const float* __restrict__ A, const float* __restrict__ A2, int lda,
    const ushort_t* __restrict__ BT, const float* __restrict__ bias,
    const float* __restrict__ resid, float* __restrict__ out, int ldo,
    int K, int gelu_flag)
{
    __shared__ __align__(16) ushort_t As[64][40];
    __shared__ __align__(16) ushort_t Bs[64][40];
    int t = threadIdx.x;
    int wid = t >> 6, lane = t & 63, l16 = lane & 15, quad = lane >> 4;
    int n0 = blockIdx.x << 6, m0 = blockIdx.y << 6;
    int srow = t >> 2, skc = (t & 3) << 3;
    f32x4 acc[4] = {{0,0,0,0},{0,0,0,0},{0,0,0,0},{0,0,0,0}};
    for (int k0 = 0; k0 < K; k0 += 32) {
        float av[8];
        const float* ap = &A[(size_t)(m0+srow)*lda + k0 + skc];
        *(float4*)&av[0] = *(const float4*)ap;
        *(float4*)&av[4] = *(const float4*)(ap + 4);
        if (A2) {
            const float* ap2 = &A2[(size_t)(m0+srow)*lda + k0 + skc];
            float4 x0 = *(const float4*)ap2;
            float4 x1 = *(const float4*)(ap2 + 4);
            av[0]+=x0.x; av[1]+=x0.y; av[2]+=x0.z; av[3]+=x0.w;
            av[4]+=x1.x; av[5]+=x1.y; av[6]+=x1.z; av[7]+=x1.w;
        }
        uint4 bv4 = *(const uint4*)&BT[(size_t)(n0+srow)*K + k0 + skc];
        ushort_t ac[8];
        #pragma unroll
        for (int i = 0; i < 8; ++i) ac[i] = f2bf(av[i]);
        __syncthreads();
        *(uint4*)&As[srow][skc] = *(uint4*)ac;
        *(uint4*)&Bs[srow][skc] = bv4;
        __syncthreads();
        s16x8 af = *(const s16x8*)&As[wid*16 + l16][quad*8];
        #pragma unroll
        for (int j = 0; j < 4; ++j) {
            s16x8 bf = *(const s16x8*)&Bs[j*16 + l16][quad*8];
            acc[j] = __builtin_amdgcn_mfma_f32_16x16x32_bf16(af, bf, acc[j], 0, 0, 0);
        }
    }
    #pragma unroll
    for (int j = 0; j < 4; ++j) {
        int col = n0 + j*16 + l16;
        float bv = bias[col];
        #pragma unroll
        for (int r = 0; r < 4; ++r) {
            int row = m0 + wid*16 + quad*4 + r;
            float v = acc[j][r] + bv;
            if (gelu_flag) v = 0.5f * v * (1.0f + erff(v * 0.70710678118654752f));
            size_t off = (size_t)row*ldo + col;
            if (resid) v += resid[off];
            out[off] = v;
        }
    }
}

// ---------------- pack: theta-shift + cast to bf16, head-major; V transposed ----------------
// input qkv [M][768] (q|k|v); qb,kb: [b][n][l][32] bf16 ; vbT: [b][n][32][l] bf16
__global__ __launch_bounds__(256) void pack_qkv(
    const float* __restrict__ qkv,
    const float* __restrict__ sp, const float* __restrict__ cp,
    ushort_t* __restrict__ qb, ushort_t* __restrict__ kb, ushort_t* __restrict__ vbT)
{
    __shared__ __align__(16) ushort_t Vl[64][40];
    int t = threadIdx.x;
    int l0 = blockIdx.x << 6;
    int n = blockIdx.y;
    int b = blockIdx.z;
    {
        int ll = t >> 2, dc = (t & 3) << 3;
        int l = l0 + ll;
        size_t gbase = ((size_t)(b*Ln + l))*768 + n*Dh + dc;
        float qx[8], kx[8], vx[8], sv[8], cv[8];
        *(float4*)&qx[0] = *(const float4*)&qkv[gbase];
        *(float4*)&qx[4] = *(const float4*)&qkv[gbase+4];
        *(float4*)&kx[0] = *(const float4*)&qkv[gbase+256];
        *(float4*)&kx[4] = *(const float4*)&qkv[gbase+260];
        *(float4*)&vx[0] = *(const float4*)&qkv[gbase+512];
        *(float4*)&vx[4] = *(const float4*)&qkv[gbase+516];
        size_t scb = (size_t)l*Dh + dc;
        *(float4*)&sv[0] = *(const float4*)&sp[scb];
        *(float4*)&sv[4] = *(const float4*)&sp[scb+4];
        *(float4*)&cv[0] = *(const float4*)&cp[scb];
        *(float4*)&cv[4] = *(const float4*)&cp[scb+4];
        ushort_t qo[8], ko[8], vo[8];
        #pragma unroll
        for (int j = 0; j < 8; j += 2) {
            float q0 = qx[j]*cv[j] - qx[j+1]*sv[j];
            float q1 = qx[j+1]*cv[j+1] + qx[j]*sv[j+1];
            float k0 = kx[j]*cv[j] - kx[j+1]*sv[j];
            float k1 = kx[j+1]*cv[j+1] + kx[j]*sv[j+1];
            qo[j] = f2bf(q0); qo[j+1] = f2bf(q1);
            ko[j] = f2bf(k0); ko[j+1] = f2bf(k1);
            vo[j] = f2bf(vx[j]); vo[j+1] = f2bf(vx[j+1]);
        }
        size_t hbase = ((size_t)((b*Nh + n)*Ln + l))*Dh + dc;
        *(uint4*)&qb[hbase] = *(uint4*)qo;
        *(uint4*)&kb[hbase] = *(uint4*)ko;
        *(uint4*)&Vl[ll][dc] = *(uint4*)vo;
    }
    __syncthreads();
    {
        int d = t >> 3, lc = (t & 7) << 3;
        ushort_t tmp[8];
        #pragma unroll
        for (int i = 0; i < 8; ++i) tmp[i] = Vl[lc + i][d];
        size_t tbase = ((size_t)((b*Nh + n)*Dh + d))*Ln + l0 + lc;
        *(uint4*)&vbT[tbase] = *(uint4*)tmp;
    }
}

// ---------------- MFMA flash attention, batch-merged ----------------
// 512 thr / 8 waves; block = 64 q-rows x both batches of one (l0,n).
// wave wid: batch bb=wid&1, q-rows l0 + (wid>>1)*16 .. +15. Twin waves share mask loads (L1).
__global__ __launch_bounds__(512) void flash_mfma(
    const ushort_t* __restrict__ qb, const ushort_t* __restrict__ kb,
    const ushort_t* __restrict__ vbT, const float* __restrict__ mask,
    float* __restrict__ out)
{
    __shared__ __align__(16) ushort_t Kt[2][64][40];   // [b][key][d]
    __shared__ __align__(16) ushort_t Vt[2][32][72];   // [b][d][key]
    __shared__ __align__(16) ushort_t Ps[8][16][72];   // per-wave P tile
    int t = threadIdx.x;
    int wid = t >> 6, lane = t & 63, l16 = lane & 15, quad = lane >> 4;
    int bb = wid & 1, wq16 = wid >> 1;
    int l0 = blockIdx.x << 6;
    int n = blockIdx.y;

    const ushort_t* qbp = qb + ((size_t)(bb*Nh + n))*Ln*Dh;
    s16x8 qfrag = *(const s16x8*)(qbp + (size_t)(l0 + wq16*16 + l16)*Dh + quad*8);
    const float* mbase = mask + (size_t)n*Ln*Ln + (size_t)(l0 + wq16*16 + quad*4)*Ln;

    // staging: 512 threads cover both batches
    int sb   = t >> 8;                    // staging batch
    int krow = (t >> 2) & 63, kkc = (t & 3) << 3;
    int vrow = (t >> 3) & 31, vkc = (t & 7) << 3;
    const ushort_t* kst = kb  + ((size_t)(sb*Nh + n))*Ln*Dh;
    const ushort_t* vst = vbT + ((size_t)((sb*Nh + n)*Dh + vrow))*Ln;

    f32x4 O0 = {0.f,0.f,0.f,0.f}, O1 = {0.f,0.f,0.f,0.f};
    float m_[4], l_[4];
    #pragma unroll
    for (int r = 0; r < 4; ++r) { m_[r] = -INFINITY; l_[r] = 0.f; }

    for (int m0 = 0; m0 < Ln; m0 += 64) {
        __syncthreads();
        *(uint4*)&Kt[sb][krow][kkc] = *(const uint4*)(kst + (size_t)(m0 + krow)*Dh + kkc);
        *(uint4*)&Vt[sb][vrow][vkc] = *(const uint4*)(vst + m0 + vkc);
        __syncthreads();

        f32x4 c0, c1, c2, c3;
        #pragma unroll
        for (int r = 0; r < 4; ++r) {
            const float* mr = mbase + (size_t)r*Ln + m0 + l16;
            c0[r] = mr[0]; c1[r] = mr[16]; c2[r] = mr[32]; c3[r] = mr[48];
        }
        f32x4 S[4];
        {
            s16x8 kf0 = *(const s16x8*)&Kt[bb][ 0 + l16][quad*8];
            s16x8 kf1 = *(const s16x8*)&Kt[bb][16 + l16][quad*8];
            s16x8 kf2 = *(const s16x8*)&Kt[bb][32 + l16][quad*8];
            s16x8 kf3 = *(const s16x8*)&Kt[bb][48 + l16][quad*8];
            S[0] = __builtin_amdgcn_mfma_f32_16x16x32_bf16(qfrag, kf0, c0, 0, 0, 0);
            S[1] = __builtin_amdgcn_mfma_f32_16x16x32_bf16(qfrag, kf1, c1, 0, 0, 0);
            S[2] = __builtin_amdgcn_mfma_f32_16x16x32_bf16(qfrag, kf2, c2, 0, 0, 0);
            S[3] = __builtin_amdgcn_mfma_f32_16x16x32_bf16(qfrag, kf3, c3, 0, 0, 0);
        }
        #pragma unroll
        for (int r = 0; r < 4; ++r) {
            float tm = fmaxf(fmaxf(S[0][r], S[1][r]), fmaxf(S[2][r], S[3][r]));
            tm = fmaxf(tm, __shfl_xor(tm, 1));
            tm = fmaxf(tm, __shfl_xor(tm, 2));
            tm = fmaxf(tm, __shfl_xor(tm, 4));
            tm = fmaxf(tm, __shfl_xor(tm, 8));
            float nm = fmaxf(m_[r], tm);
            float al = __expf(m_[r] - nm);
            m_[r] = nm;
            float p0 = __expf(S[0][r] - nm);
            float p1 = __expf(S[1][r] - nm);
            float p2 = __expf(S[2][r] - nm);
            float p3 = __expf(S[3][r] - nm);
            float ps = p0 + p1 + p2 + p3;
            ps += __shfl_xor(ps, 1); ps += __shfl_xor(ps, 2);
            ps += __shfl_xor(ps, 4); ps += __shfl_xor(ps, 8);
            l_[r] = l_[r]*al + ps;
            O0[r] *= al; O1[r] *= al;
            int rr = quad*4 + r;
            Ps[wid][rr][ 0 + l16] = f2bf(p0);
            Ps[wid][rr][16 + l16] = f2bf(p1);
            Ps[wid][rr][32 + l16] = f2bf(p2);
            Ps[wid][rr][48 + l16] = f2bf(p3);
        }
        #pragma unroll
        for (int kc = 0; kc < 2; ++kc) {
            s16x8 pf  = *(const s16x8*)&Ps[wid][l16][kc*32 + quad*8];
            s16x8 vf0 = *(const s16x8*)&Vt[bb][ 0 + l16][kc*32 + quad*8];
            s16x8 vf1 = *(const s16x8*)&Vt[bb][16 + l16][kc*32 + quad*8];
            O0 = __builtin_amdgcn_mfma_f32_16x16x32_bf16(pf, vf0, O0, 0, 0, 0);
            O1 = __builtin_amdgcn_mfma_f32_16x16x32_bf16(pf, vf1, O1, 0, 0, 0);
        }
    }
    #pragma unroll
    for (int r = 0; r < 4; ++r) {
        float inv = 1.0f / l_[r];
        size_t row = (size_t)(bb*Ln + l0 + wq16*16 + quad*4 + r)*Cn + n*Dh;
        out[row + l16]      = O0[r] * inv;
        out[row + 16 + l16] = O1[r] * inv;
    }
}

extern "C" void kernel_launch(void* const* d_in, const int* in_sizes, int n_in,
                              void* d_out, int out_size, void* d_ws, size_t ws_size,
                              hipStream_t stream) {
    const float* x     = (const float*)d_in[0];
    const float* sinp  = (const float*)d_in[1];
    const float* cosp  = (const float*)d_in[2];
    const float* mask  = (const float*)d_in[3];
    const float* pos_w = (const float*)d_in[4];
    const float* pos_b = (const float*)d_in[5];
    const float* ln1_g = (const float*)d_in[6];
    const float* ln1_b = (const float*)d_in[7];
    const float* wq = (const float*)d_in[8];
    const float* bq = (const float*)d_in[9];
    const float* wk = (const float*)d_in[10];
    const float* bk = (const float*)d_in[11];
    const float* wv = (const float*)d_in[12];
    const float* bv = (const float*)d_in[13];
    const float* lepe_w = (const float*)d_in[14];
    const float* lepe_b = (const float*)d_in[15];
    const float* wo = (const float*)d_in[16];
    const float* bo = (const float*)d_in[17];
    const float* ln2_g = (const float*)d_in[18];
    const float* ln2_b = (const float*)d_in[19];
    const float* w1 = (const float*)d_in[20];
    const float* b1 = (const float*)d_in[21];
    const float* ffn_w = (const float*)d_in[22];
    const float* ffn_b = (const float*)d_in[23];
    const float* w2 = (const float*)d_in[24];
    const float* b2 = (const float*)d_in[25];

    float* ws = (float*)d_ws;
    const size_t MC = (size_t)Mrows*Cn;   // 1,605,632 floats
    // layout (MC units):
    // 0 xbuf | 1..4 qkv [M][768] | 4 ybuf/zbuf | 5 lepe | 6 x2 | 7 att | 8..12 z1 | 12..16 z2
    // 16..17.5: qb, kb, vbT (bf16) | 17.5+: weights
    float* xbuf = ws;
    float* qkv  = ws + MC;
    float* ybuf = ws + 4*MC;
    float* lepe = ws + 5*MC;
    float* x2   = ws + 6*MC;
    float* att  = ws + 7*MC;
    float* z1   = ws + 8*MC;
    float* z2   = ws + 12*MC;
    ushort_t* qb  = (ushort_t*)(ws + 16*MC);
    ushort_t* kb  = (ushort_t*)(ws + 16*MC + MC/2);
    ushort_t* vbT = (ushort_t*)(ws + 17*MC);
    float* wtb = ws + 17*MC + MC/2;
    ushort_t* wqkvT = (ushort_t*)wtb;                    // 196608 bf16 = 98304 fl
    ushort_t* woT   = (ushort_t*)(wtb + 98304);          // 65536 bf16 = 32768 fl
    ushort_t* w1T   = (ushort_t*)(wtb + 131072);         // 262144 bf16 = 131072 fl
    ushort_t* w2T   = (ushort_t*)(wtb + 262144);         // 262144 bf16 = 131072 fl
    float*    bqkv  = wtb + 393216;                      // 768 fl
    float* outp = (float*)d_out;

    int totalC = Mrows*Cn/4;
    int totalF = Mrows*Fn/4;
    dim3 fg(Ln/64, Nh, Bn);
    dim3 fg2(Ln/64, Nh);

    // 0. weights: transpose + bf16 (every call; ws is re-poisoned)
    prep_weights<<<(787200+255)/256, 256, 0, stream>>>(wq,bq,wk,bk,wv,bv,wo,w1,w2,
                                                       wqkvT,bqkv,woT,w1T,w2T);
    // 1. x = x + dwconv3x3(x)
    dwconv_kernel<<<(totalC+255)/256, 256, 0, stream>>>(x, pos_w, pos_b, xbuf, Cn, Cn, Cn, 3, 1, 1);
    // 2. y = LN1(x)
    ln_kernel<<<Mrows, 256, 0, stream>>>(xbuf, ln1_g, ln1_b, ybuf);
    // 3. qkv = y @ [wq|wk*s|wv] + [bq|bk*s|bv]
    gemm_bf16<<<dim3(12, Mrows/64), 256, 0, stream>>>(ybuf, nullptr, Cn, wqkvT, bqkv,
                                                      nullptr, qkv, 768, Cn, 0);
    // 4. pack: theta shift + bf16 head-major + V transpose
    pack_qkv<<<fg, 256, 0, stream>>>(qkv, sinp, cosp, qb, kb, vbT);
    // 5. lepe = dwconv5x5(v)
    dwconv_kernel<<<(totalC+255)/256, 256, 0, stream>>>(qkv+512, lepe_w, lepe_b, lepe, Cn, 768, Cn, 5, 2, 0);
    // 6. attention (MFMA, batch-merged)
    flash_mfma<<<fg2, 512, 0, stream>>>(qb, kb, vbT, mask, att);
    // 7. x2 = x + (att + lepe) @ wo + bo
    gemm_bf16<<<dim3(4, Mrows/64), 256, 0, stream>>>(att, lepe, Cn, woT, bo, xbuf, x2, Cn, Cn, 0);
    // 8. z = LN2(x2)  (zbuf = ybuf, dead)
    ln_kernel<<<Mrows, 256, 0, stream>>>(x2, ln2_g, ln2_b, ybuf);
    // 9. z1 = gelu(z @ w1 + b1)
    gemm_bf16<<<dim3(16, Mrows/64), 256, 0, stream>>>(ybuf, nullptr, Cn, w1T, b1, nullptr, z1, Fn, Cn, 1);
    // 10. z2 = z1 + dwconv3x3(z1)
    dwconv_kernel<<<(totalF+255)/256, 256, 0, stream>>>(z1, ffn_w, ffn_b, z2, Fn, Fn, Fn, 3, 1, 1);
    // 11. out = x2 + z2 @ w2 + b2
    gemm_bf16<<<dim3(4, Mrows/64), 256, 0, stream>>>(z2, nullptr, Fn, w2T, b2, x2, outp, Cn, Fn, 0);
}

// Round 4
// 657.755 us; speedup vs baseline: 5.3756x; 1.0392x over previous
//
#include <hip/hip_runtime.h>
#include <hip/hip_bf16.h>
#include <math.h>

#define Bn 2
#define Hn 56
#define Wn 56
#define Cn 256
#define Nh 8
#define Dh 32
#define Fn 1024
#define Ln (Hn*Wn)          // 3136
#define Mrows (Bn*Ln)       // 6272
#define SCALING_K 0.17677669529663687f   // 32^-0.5

typedef __attribute__((ext_vector_type(4))) float f32x4;
typedef __attribute__((ext_vector_type(8))) short s16x8;
typedef unsigned short ushort_t;

__device__ __forceinline__ ushort_t f2bf(float f) {
    __hip_bfloat16 h = __float2bfloat16(f);
    return *reinterpret_cast<ushort_t*>(&h);
}

// ---------------- weight transpose: fp32 [K][N] -> bf16 [N][K], LDS-tiled ----------------
__global__ __launch_bounds__(256) void transpose_w(
    const float* __restrict__ wq, const float* __restrict__ wk, const float* __restrict__ wv,
    const float* __restrict__ wo, const float* __restrict__ w1, const float* __restrict__ w2,
    ushort_t* __restrict__ wqkvT, ushort_t* __restrict__ woT,
    ushort_t* __restrict__ w1T, ushort_t* __restrict__ w2T)
{
    int z = blockIdx.z;
    const float* src; ushort_t* dst; int K, N; float scale = 1.f;
    switch (z) {
      case 0: src=wq; dst=wqkvT;           K=256;  N=256;  break;
      case 1: src=wk; dst=wqkvT+256*256;   K=256;  N=256;  scale=SCALING_K; break;
      case 2: src=wv; dst=wqkvT+512*256;   K=256;  N=256;  break;
      case 3: src=wo; dst=woT;             K=256;  N=256;  break;
      case 4: src=w1; dst=w1T;             K=256;  N=1024; break;
      default: src=w2; dst=w2T;            K=1024; N=256;  break;
    }
    int n0 = blockIdx.x << 5, k0 = blockIdx.y << 5;
    if (n0 >= N || k0 >= K) return;
    __shared__ float tile[32][33];
    int tx = threadIdx.x & 31, ty = threadIdx.x >> 5;   // 32 x 8
    #pragma unroll
    for (int r = 0; r < 4; ++r)
        tile[ty + 8*r][tx] = src[(size_t)(k0 + ty + 8*r)*N + n0 + tx] * scale;
    __syncthreads();
    #pragma unroll
    for (int r = 0; r < 4; ++r)
        dst[(size_t)(n0 + ty + 8*r)*K + k0 + tx] = f2bf(tile[tx][ty + 8*r]);
}

__global__ void prep_bias(const float* __restrict__ bq, const float* __restrict__ bk,
                          const float* __restrict__ bv, float* __restrict__ bqkv)
{
    int i = blockIdx.x*256 + threadIdx.x;
    if (i < 768)
        bqkv[i] = (i < 256) ? bq[i] : (i < 512 ? bk[i-256]*SCALING_K : bv[i-512]);
}

// ---------------- pos dwconv3x3 + residual + LN1 stats, 4 pixels/thread ----------------
// block: 16 pixels (4 pixel-quads) x 64 channel-groups; one wave per pixel-quad.
__global__ __launch_bounds__(256) void dwconv_ln(
    const float* __restrict__ x, const float* __restrict__ wgt, const float* __restrict__ bias,
    float* __restrict__ out, float2* __restrict__ stats)
{
    int t = threadIdx.x;
    int cg = t & 63;
    int g = blockIdx.x*4 + (t >> 6);       // pixel-quad index
    int w0 = (g % 14) << 2;
    int hr = g / 14;                        // b*Hn + h
    int h = hr % Hn;
    int c = cg << 2;
    float4 wv9[9];
    #pragma unroll
    for (int i = 0; i < 9; ++i) wv9[i] = *(const float4*)&wgt[i*Cn + c];
    float4 bias4 = *(const float4*)&bias[c];
    float4 acc[4] = {bias4, bias4, bias4, bias4};
    const float* base = x + (size_t)(hr - h)*Wn*Cn + c;
    #pragma unroll
    for (int dh = 0; dh < 3; ++dh) {
        int hh = h + dh - 1;
        if (hh < 0 || hh >= Hn) continue;
        const float* rowp = base + (size_t)hh*Wn*Cn;
        float4 xv[6];
        #pragma unroll
        for (int j = 0; j < 6; ++j) {
            int wc = w0 - 1 + j;
            xv[j] = (wc >= 0 && wc < Wn) ? *(const float4*)&rowp[(size_t)wc*Cn]
                                         : make_float4(0.f,0.f,0.f,0.f);
        }
        #pragma unroll
        for (int dw = 0; dw < 3; ++dw) {
            float4 wv = wv9[dh*3 + dw];
            #pragma unroll
            for (int p = 0; p < 4; ++p) {
                acc[p].x += xv[p+dw].x*wv.x; acc[p].y += xv[p+dw].y*wv.y;
                acc[p].z += xv[p+dw].z*wv.z; acc[p].w += xv[p+dw].w*wv.w;
            }
        }
        if (dh == 1) {
            #pragma unroll
            for (int p = 0; p < 4; ++p) {
                acc[p].x += xv[p+1].x; acc[p].y += xv[p+1].y;
                acc[p].z += xv[p+1].z; acc[p].w += xv[p+1].w;
            }
        }
    }
    float s[4], q[4];
    #pragma unroll
    for (int p = 0; p < 4; ++p) {
        s[p] = acc[p].x + acc[p].y + acc[p].z + acc[p].w;
        q[p] = acc[p].x*acc[p].x + acc[p].y*acc[p].y + acc[p].z*acc[p].z + acc[p].w*acc[p].w;
    }
    #pragma unroll
    for (int m = 1; m < 64; m <<= 1) {
        #pragma unroll
        for (int p = 0; p < 4; ++p) {
            s[p] += __shfl_xor(s[p], m);
            q[p] += __shfl_xor(q[p], m);
        }
    }
    size_t pixbase = (size_t)hr*Wn + w0;
    #pragma unroll
    for (int p = 0; p < 4; ++p)
        *(float4*)&out[(pixbase + p)*Cn + c] = acc[p];
    if (cg == 0) {
        #pragma unroll
        for (int p = 0; p < 4; ++p) {
            float mean = s[p] * (1.0f/Cn);
            float var  = q[p] * (1.0f/Cn) - mean*mean;
            stats[pixbase + p] = make_float2(mean, rsqrtf(var + 1e-6f));
        }
    }
}

// ---------------- generic dwconv, 4 pixels/thread, optional bf16 out ----------------
template<int KS, int OBF>
__global__ __launch_bounds__(256) void dwconv4(
    const float* __restrict__ in, const float* __restrict__ wgt, const float* __restrict__ bias,
    void* __restrict__ outv, int C, int inld, int addin)
{
    constexpr int PAD = KS/2;
    int t = threadIdx.x;
    int cgs = C >> 2;
    int qpb = 256 / cgs;
    int cg = t % cgs;
    int g = blockIdx.x*qpb + t/cgs;
    int w0 = (g % 14) << 2;
    int hr = g / 14;
    int h = hr % Hn;
    int c = cg << 2;
    float4 bias4 = *(const float4*)&bias[c];
    float4 acc[4] = {bias4, bias4, bias4, bias4};
    const float* base = in + (size_t)(hr - h)*Wn*inld + c;
    #pragma unroll
    for (int dh = 0; dh < KS; ++dh) {
        int hh = h + dh - PAD;
        if (hh < 0 || hh >= Hn) continue;
        const float* rowp = base + (size_t)hh*Wn*inld;
        float4 xv[KS+3];
        #pragma unroll
        for (int j = 0; j < KS+3; ++j) {
            int wc = w0 - PAD + j;
            xv[j] = (wc >= 0 && wc < Wn) ? *(const float4*)&rowp[(size_t)wc*inld]
                                         : make_float4(0.f,0.f,0.f,0.f);
        }
        #pragma unroll
        for (int dw = 0; dw < KS; ++dw) {
            float4 wv = *(const float4*)&wgt[(dh*KS + dw)*C + c];
            #pragma unroll
            for (int p = 0; p < 4; ++p) {
                acc[p].x += xv[p+dw].x*wv.x; acc[p].y += xv[p+dw].y*wv.y;
                acc[p].z += xv[p+dw].z*wv.z; acc[p].w += xv[p+dw].w*wv.w;
            }
        }
        if (addin && dh == PAD) {
            #pragma unroll
            for (int p = 0; p < 4; ++p) {
                acc[p].x += xv[p+PAD].x; acc[p].y += xv[p+PAD].y;
                acc[p].z += xv[p+PAD].z; acc[p].w += xv[p+PAD].w;
            }
        }
    }
    size_t pixbase = (size_t)hr*Wn + w0;
    if (OBF) {
        ushort_t* outb = (ushort_t*)outv;
        #pragma unroll
        for (int p = 0; p < 4; ++p) {
            ushort_t tmp[4] = { f2bf(acc[p].x), f2bf(acc[p].y), f2bf(acc[p].z), f2bf(acc[p].w) };
            *(uint2*)&outb[(pixbase + p)*C + c] = *(uint2*)tmp;
        }
    } else {
        float* outf = (float*)outv;
        #pragma unroll
        for (int p = 0; p < 4; ++p)
            *(float4*)&outf[(pixbase + p)*C + c] = acc[p];
    }
}

// ---------------- LN stats only (mean, rstd) over C=256 ----------------
__global__ __launch_bounds__(256) void ln_stats(const float* __restrict__ in, float2* __restrict__ stats)
{
    int row = blockIdx.x;
    int t = threadIdx.x;
    float v = in[(size_t)row*Cn + t];
    float s1 = v, s2 = v*v;
    #pragma unroll
    for (int m = 1; m < 64; m <<= 1) {
        s1 += __shfl_xor(s1, m);
        s2 += __shfl_xor(s2, m);
    }
    __shared__ float w1s[4], w2s[4];
    if ((t & 63) == 0) { w1s[t>>6] = s1; w2s[t>>6] = s2; }
    __syncthreads();
    if (t == 0) {
        s1 = w1s[0]+w1s[1]+w1s[2]+w1s[3];
        s2 = w2s[0]+w2s[1]+w2s[2]+w2s[3];
        float mean = s1 * (1.0f/Cn);
        float var  = s2 * (1.0f/Cn) - mean*mean;
        stats[row] = make_float2(mean, rsqrtf(var + 1e-6f));
    }
}

// ---------------- bf16 MFMA GEMM with optional fused LN on A, bias/gelu/resid epilogue ----------------
// tile 64(M)x64(N), BK=32, 256 thr / 4 waves. grid.x = N/64, grid.y = M/64.
__global__ __launch_bounds__(256) void gemm_bf16(
    const void* __restrict__ Av, int abf16, const float* __restrict__ A2, int lda,
    const float2* __restrict__ lnstat, const float* __restrict__ lng, const float* __restrict__ lnb,
    const ushort_t* __restrict__ BT, const float* __restrict__ bias,
    const float* __restrict__ resid, float* __restrict__ out, int ldo,
    int K, int gelu_flag)
{
    __shared__ __align__(16) ushort_t As[64][40];
    __shared__ __align__(16) ushort_t Bs[64][40];
    int t = threadIdx.x;
    int wid = t >> 6, lane = t & 63, l16 = lane & 15, quad = lane >> 4;
    int n0 = blockIdx.x << 6, m0 = blockIdx.y << 6;
    int srow = t >> 2, skc = (t & 3) << 3;
    float2 st = make_float2(0.f, 1.f);
    if (lnstat) st = lnstat[m0 + srow];
    f32x4 acc[4] = {{0,0,0,0},{0,0,0,0},{0,0,0,0},{0,0,0,0}};
    for (int k0 = 0; k0 < K; k0 += 32) {
        ushort_t ac[8];
        if (abf16) {
            *(uint4*)ac = *(const uint4*)&((const ushort_t*)Av)[(size_t)(m0+srow)*lda + k0 + skc];
        } else {
            float av[8];
            const float* ap = &((const float*)Av)[(size_t)(m0+srow)*lda + k0 + skc];
            *(float4*)&av[0] = *(const float4*)ap;
            *(float4*)&av[4] = *(const float4*)(ap + 4);
            if (A2) {
                const float* ap2 = &A2[(size_t)(m0+srow)*lda + k0 + skc];
                float4 x0 = *(const float4*)ap2;
                float4 x1 = *(const float4*)(ap2 + 4);
                av[0]+=x0.x; av[1]+=x0.y; av[2]+=x0.z; av[3]+=x0.w;
                av[4]+=x1.x; av[5]+=x1.y; av[6]+=x1.z; av[7]+=x1.w;
            }
            if (lnstat) {
                float gg[8], bb[8];
                *(float4*)&gg[0] = *(const float4*)&lng[k0 + skc];
                *(float4*)&gg[4] = *(const float4*)&lng[k0 + skc + 4];
                *(float4*)&bb[0] = *(const float4*)&lnb[k0 + skc];
                *(float4*)&bb[4] = *(const float4*)&lnb[k0 + skc + 4];
                #pragma unroll
                for (int i = 0; i < 8; ++i)
                    av[i] = (av[i] - st.x)*st.y*gg[i] + bb[i];
            }
            #pragma unroll
            for (int i = 0; i < 8; ++i) ac[i] = f2bf(av[i]);
        }
        uint4 bv4 = *(const uint4*)&BT[(size_t)(n0+srow)*K + k0 + skc];
        __syncthreads();
        *(uint4*)&As[srow][skc] = *(uint4*)ac;
        *(uint4*)&Bs[srow][skc] = bv4;
        __syncthreads();
        s16x8 af = *(const s16x8*)&As[wid*16 + l16][quad*8];
        #pragma unroll
        for (int j = 0; j < 4; ++j) {
            s16x8 bf = *(const s16x8*)&Bs[j*16 + l16][quad*8];
            acc[j] = __builtin_amdgcn_mfma_f32_16x16x32_bf16(af, bf, acc[j], 0, 0, 0);
        }
    }
    #pragma unroll
    for (int j = 0; j < 4; ++j) {
        int col = n0 + j*16 + l16;
        float bv = bias[col];
        #pragma unroll
        for (int r = 0; r < 4; ++r) {
            int row = m0 + wid*16 + quad*4 + r;
            float v = acc[j][r] + bv;
            if (gelu_flag) v = 0.5f * v * (1.0f + erff(v * 0.70710678118654752f));
            size_t off = (size_t)row*ldo + col;
            if (resid) v += resid[off];
            out[off] = v;
        }
    }
}

// ---------------- pack: theta-shift + cast to bf16, head-major; V transposed ----------------
__global__ __launch_bounds__(256) void pack_qkv(
    const float* __restrict__ qkv,
    const float* __restrict__ sp, const float* __restrict__ cp,
    ushort_t* __restrict__ qb, ushort_t* __restrict__ kb, ushort_t* __restrict__ vbT)
{
    __shared__ __align__(16) ushort_t Vl[64][40];
    int t = threadIdx.x;
    int l0 = blockIdx.x << 6;
    int n = blockIdx.y;
    int b = blockIdx.z;
    {
        int ll = t >> 2, dc = (t & 3) << 3;
        int l = l0 + ll;
        size_t gbase = ((size_t)(b*Ln + l))*768 + n*Dh + dc;
        float qx[8], kx[8], vx[8], sv[8], cv[8];
        *(float4*)&qx[0] = *(const float4*)&qkv[gbase];
        *(float4*)&qx[4] = *(const float4*)&qkv[gbase+4];
        *(float4*)&kx[0] = *(const float4*)&qkv[gbase+256];
        *(float4*)&kx[4] = *(const float4*)&qkv[gbase+260];
        *(float4*)&vx[0] = *(const float4*)&qkv[gbase+512];
        *(float4*)&vx[4] = *(const float4*)&qkv[gbase+516];
        size_t scb = (size_t)l*Dh + dc;
        *(float4*)&sv[0] = *(const float4*)&sp[scb];
        *(float4*)&sv[4] = *(const float4*)&sp[scb+4];
        *(float4*)&cv[0] = *(const float4*)&cp[scb];
        *(float4*)&cv[4] = *(const float4*)&cp[scb+4];
        ushort_t qo[8], ko[8], vo[8];
        #pragma unroll
        for (int j = 0; j < 8; j += 2) {
            float q0 = qx[j]*cv[j] - qx[j+1]*sv[j];
            float q1 = qx[j+1]*cv[j+1] + qx[j]*sv[j+1];
            float k0 = kx[j]*cv[j] - kx[j+1]*sv[j];
            float k1 = kx[j+1]*cv[j+1] + kx[j]*sv[j+1];
            qo[j] = f2bf(q0); qo[j+1] = f2bf(q1);
            ko[j] = f2bf(k0); ko[j+1] = f2bf(k1);
            vo[j] = f2bf(vx[j]); vo[j+1] = f2bf(vx[j+1]);
        }
        size_t hbase = ((size_t)((b*Nh + n)*Ln + l))*Dh + dc;
        *(uint4*)&qb[hbase] = *(uint4*)qo;
        *(uint4*)&kb[hbase] = *(uint4*)ko;
        *(uint4*)&Vl[ll][dc] = *(uint4*)vo;
    }
    __syncthreads();
    {
        int d = t >> 3, lc = (t & 7) << 3;
        ushort_t tmp[8];
        #pragma unroll
        for (int i = 0; i < 8; ++i) tmp[i] = Vl[lc + i][d];
        size_t tbase = ((size_t)((b*Nh + n)*Dh + d))*Ln + l0 + lc;
        *(uint4*)&vbT[tbase] = *(uint4*)tmp;
    }
}

// ---------------- MFMA flash attention, batch-merged, register-prefetch pipeline ----------------
__global__ __launch_bounds__(512) void flash_mfma(
    const ushort_t* __restrict__ qb, const ushort_t* __restrict__ kb,
    const ushort_t* __restrict__ vbT, const float* __restrict__ mask,
    float* __restrict__ out)
{
    __shared__ __align__(16) ushort_t Kt[2][64][40];   // [b][key][d]
    __shared__ __align__(16) ushort_t Vt[2][32][72];   // [b][d][key]
    __shared__ __align__(16) ushort_t Ps[8][16][72];   // per-wave P tile
    int t = threadIdx.x;
    int wid = t >> 6, lane = t & 63, l16 = lane & 15, quad = lane >> 4;
    int bb = wid & 1, wq16 = wid >> 1;
    int l0 = blockIdx.x << 6;
    int n = blockIdx.y;

    const ushort_t* qbp = qb + ((size_t)(bb*Nh + n))*Ln*Dh;
    s16x8 qfrag = *(const s16x8*)(qbp + (size_t)(l0 + wq16*16 + l16)*Dh + quad*8);
    const float* mbase = mask + (size_t)n*Ln*Ln + (size_t)(l0 + wq16*16 + quad*4)*Ln;

    int sb   = t >> 8;
    int krow = (t >> 2) & 63, kkc = (t & 3) << 3;
    int vrow = (t >> 3) & 31, vkc = (t & 7) << 3;
    const ushort_t* kst = kb  + ((size_t)(sb*Nh + n))*Ln*Dh;
    const ushort_t* vst = vbT + ((size_t)((sb*Nh + n)*Dh + vrow))*Ln;

    f32x4 O0 = {0.f,0.f,0.f,0.f}, O1 = {0.f,0.f,0.f,0.f};
    float m_[4], l_[4];
    #pragma unroll
    for (int r = 0; r < 4; ++r) { m_[r] = -INFINITY; l_[r] = 0.f; }

    // prologue prefetch for tile 0
    uint4 kreg = *(const uint4*)(kst + (size_t)krow*Dh + kkc);
    uint4 vreg = *(const uint4*)(vst + vkc);
    f32x4 c0, c1, c2, c3;
    #pragma unroll
    for (int r = 0; r < 4; ++r) {
        const float* mr = mbase + (size_t)r*Ln + l16;
        c0[r] = mr[0]; c1[r] = mr[16]; c2[r] = mr[32]; c3[r] = mr[48];
    }

    for (int m0 = 0; m0 < Ln; m0 += 64) {
        __syncthreads();
        *(uint4*)&Kt[sb][krow][kkc] = kreg;
        *(uint4*)&Vt[sb][vrow][vkc] = vreg;
        __syncthreads();

        // prefetch next tile (in flight across this iteration's compute)
        int m1 = m0 + 64;
        uint4 krn = kreg, vrn = vreg;
        f32x4 d0 = c0, d1 = c1, d2 = c2, d3 = c3;
        if (m1 < Ln) {
            krn = *(const uint4*)(kst + (size_t)(m1 + krow)*Dh + kkc);
            vrn = *(const uint4*)(vst + m1 + vkc);
            #pragma unroll
            for (int r = 0; r < 4; ++r) {
                const float* mr = mbase + (size_t)r*Ln + m1 + l16;
                d0[r] = mr[0]; d1[r] = mr[16]; d2[r] = mr[32]; d3[r] = mr[48];
            }
        }

        f32x4 S[4];
        {
            s16x8 kf0 = *(const s16x8*)&Kt[bb][ 0 + l16][quad*8];
            s16x8 kf1 = *(const s16x8*)&Kt[bb][16 + l16][quad*8];
            s16x8 kf2 = *(const s16x8*)&Kt[bb][32 + l16][quad*8];
            s16x8 kf3 = *(const s16x8*)&Kt[bb][48 + l16][quad*8];
            S[0] = __builtin_amdgcn_mfma_f32_16x16x32_bf16(qfrag, kf0, c0, 0, 0, 0);
            S[1] = __builtin_amdgcn_mfma_f32_16x16x32_bf16(qfrag, kf1, c1, 0, 0, 0);
            S[2] = __builtin_amdgcn_mfma_f32_16x16x32_bf16(qfrag, kf2, c2, 0, 0, 0);
            S[3] = __builtin_amdgcn_mfma_f32_16x16x32_bf16(qfrag, kf3, c3, 0, 0, 0);
        }
        #pragma unroll
        for (int r = 0; r < 4; ++r) {
            float tm = fmaxf(fmaxf(S[0][r], S[1][r]), fmaxf(S[2][r], S[3][r]));
            tm = fmaxf(tm, __shfl_xor(tm, 1));
            tm = fmaxf(tm, __shfl_xor(tm, 2));
            tm = fmaxf(tm, __shfl_xor(tm, 4));
            tm = fmaxf(tm, __shfl_xor(tm, 8));
            float nm = fmaxf(m_[r], tm);
            float al = __expf(m_[r] - nm);
            m_[r] = nm;
            float p0 = __expf(S[0][r] - nm);
            float p1 = __expf(S[1][r] - nm);
            float p2 = __expf(S[2][r] - nm);
            float p3 = __expf(S[3][r] - nm);
            float ps = p0 + p1 + p2 + p3;
            ps += __shfl_xor(ps, 1); ps += __shfl_xor(ps, 2);
            ps += __shfl_xor(ps, 4); ps += __shfl_xor(ps, 8);
            l_[r] = l_[r]*al + ps;
            O0[r] *= al; O1[r] *= al;
            int rr = quad*4 + r;
            Ps[wid][rr][ 0 + l16] = f2bf(p0);
            Ps[wid][rr][16 + l16] = f2bf(p1);
            Ps[wid][rr][32 + l16] = f2bf(p2);
            Ps[wid][rr][48 + l16] = f2bf(p3);
        }
        #pragma unroll
        for (int kc = 0; kc < 2; ++kc) {
            s16x8 pf  = *(const s16x8*)&Ps[wid][l16][kc*32 + quad*8];
            s16x8 vf0 = *(const s16x8*)&Vt[bb][ 0 + l16][kc*32 + quad*8];
            s16x8 vf1 = *(const s16x8*)&Vt[bb][16 + l16][kc*32 + quad*8];
            O0 = __builtin_amdgcn_mfma_f32_16x16x32_bf16(pf, vf0, O0, 0, 0, 0);
            O1 = __builtin_amdgcn_mfma_f32_16x16x32_bf16(pf, vf1, O1, 0, 0, 0);
        }
        kreg = krn; vreg = vrn;
        c0 = d0; c1 = d1; c2 = d2; c3 = d3;
    }
    #pragma unroll
    for (int r = 0; r < 4; ++r) {
        float inv = 1.0f / l_[r];
        size_t row = (size_t)(bb*Ln + l0 + wq16*16 + quad*4 + r)*Cn + n*Dh;
        out[row + l16]      = O0[r] * inv;
        out[row + 16 + l16] = O1[r] * inv;
    }
}

extern "C" void kernel_launch(void* const* d_in, const int* in_sizes, int n_in,
                              void* d_out, int out_size, void* d_ws, size_t ws_size,
                              hipStream_t stream) {
    const float* x     = (const float*)d_in[0];
    const float* sinp  = (const float*)d_in[1];
    const float* cosp  = (const float*)d_in[2];
    const float* mask  = (const float*)d_in[3];
    const float* pos_w = (const float*)d_in[4];
    const float* pos_b = (const float*)d_in[5];
    const float* ln1_g = (const float*)d_in[6];
    const float* ln1_b = (const float*)d_in[7];
    const float* wq = (const float*)d_in[8];
    const float* bq = (const float*)d_in[9];
    const float* wk = (const float*)d_in[10];
    const float* bk = (const float*)d_in[11];
    const float* wv = (const float*)d_in[12];
    const float* bv = (const float*)d_in[13];
    const float* lepe_w = (const float*)d_in[14];
    const float* lepe_b = (const float*)d_in[15];
    const float* wo = (const float*)d_in[16];
    const float* bo = (const float*)d_in[17];
    const float* ln2_g = (const float*)d_in[18];
    const float* ln2_b = (const float*)d_in[19];
    const float* w1 = (const float*)d_in[20];
    const float* b1 = (const float*)d_in[21];
    const float* ffn_w = (const float*)d_in[22];
    const float* ffn_b = (const float*)d_in[23];
    const float* w2 = (const float*)d_in[24];
    const float* b2 = (const float*)d_in[25];

    float* ws = (float*)d_ws;
    const size_t MC = (size_t)Mrows*Cn;   // 1,605,632 floats
    float* xbuf = ws;                     // MC
    float* qkv  = ws + MC;                // 3MC   [M][768]
    float* lepe = ws + 4*MC;              // MC
    float* x2   = ws + 5*MC;              // MC
    float* att  = ws + 6*MC;              // MC
    float* z1   = ws + 7*MC;              // 4MC   [M][1024] fp32
    ushort_t* z2bf = (ushort_t*)(ws + 11*MC);   // 2MC floats worth of bf16 [M][1024]
    ushort_t* qb   = (ushort_t*)(ws + 13*MC);
    ushort_t* kb   = (ushort_t*)(ws + 13*MC + MC/2);
    ushort_t* vbT  = (ushort_t*)(ws + 14*MC);
    float* wtb = ws + 14*MC + MC/2;
    ushort_t* wqkvT = (ushort_t*)wtb;                 // 196608 us = 98304 f
    ushort_t* woT   = (ushort_t*)(wtb + 98304);       // 65536 us = 32768 f
    ushort_t* w1T   = (ushort_t*)(wtb + 131072);      // 262144 us = 131072 f
    ushort_t* w2T   = (ushort_t*)(wtb + 262144);      // 262144 us = 131072 f
    float*    bqkv  = wtb + 393216;                   // 768 f
    float2*   stats1 = (float2*)(wtb + 394240);       // Mrows float2 = 12544 f
    float2*   stats2 = (float2*)(wtb + 406784);
    float* outp = (float*)d_out;

    // 0. weight prep
    transpose_w<<<dim3(32,32,6), 256, 0, stream>>>(wq,wk,wv,wo,w1,w2, wqkvT,woT,w1T,w2T);
    prep_bias<<<3, 256, 0, stream>>>(bq,bk,bv,bqkv);
    // 1. xbuf = x + dwconv3x3(x); LN1 stats fused
    dwconv_ln<<<Mrows/16, 256, 0, stream>>>(x, pos_w, pos_b, xbuf, stats1);
    // 2. qkv = LN1(xbuf) @ [wq|wk*s|wv] + [bq|bk*s|bv]   (LN applied in staging)
    gemm_bf16<<<dim3(12, Mrows/64), 256, 0, stream>>>(xbuf, 0, nullptr, Cn,
        stats1, ln1_g, ln1_b, wqkvT, bqkv, nullptr, qkv, 768, Cn, 0);
    // 3. pack: theta shift + bf16 head-major + V transpose
    pack_qkv<<<dim3(Ln/64, Nh, Bn), 256, 0, stream>>>(qkv, sinp, cosp, qb, kb, vbT);
    // 4. lepe = dwconv5x5(v)
    dwconv4<5,0><<<Mrows/16, 256, 0, stream>>>(qkv+512, lepe_w, lepe_b, lepe, Cn, 768, 0);
    // 5. attention
    flash_mfma<<<dim3(Ln/64, Nh), 512, 0, stream>>>(qb, kb, vbT, mask, att);
    // 6. x2 = xbuf + (att + lepe) @ wo + bo
    gemm_bf16<<<dim3(4, Mrows/64), 256, 0, stream>>>(att, 0, lepe, Cn,
        nullptr, nullptr, nullptr, woT, bo, xbuf, x2, Cn, Cn, 0);
    // 7. LN2 stats
    ln_stats<<<Mrows, 256, 0, stream>>>(x2, stats2);
    // 8. z1 = gelu(LN2(x2) @ w1 + b1)
    gemm_bf16<<<dim3(16, Mrows/64), 256, 0, stream>>>(x2, 0, nullptr, Cn,
        stats2, ln2_g, ln2_b, w1T, b1, nullptr, z1, Fn, Cn, 1);
    // 9. z2 = z1 + dwconv3x3(z1), stored bf16
    dwconv4<3,1><<<Mrows/4, 256, 0, stream>>>(z1, ffn_w, ffn_b, z2bf, Fn, Fn, 1);
    // 10. out = x2 + z2 @ w2 + b2
    gemm_bf16<<<dim3(4, Mrows/64), 256, 0, stream>>>(z2bf, 1, nullptr, Fn,
        nullptr, nullptr, nullptr, w2T, b2, x2, outp, Cn, Fn, 0);
}